// Round 1
// baseline (12133.413 us; speedup 1.0000x reference)
//
#include <hip/hip_runtime.h>
#include <math.h>

#define HW 65536
#define Wd 256
#define Hd 256
#define Bn 4

// ---------------- conv 1x1 : thread per pixel, all COUT channels ----------------
template<int CIN,int COUT>
__global__ void conv1x1_k(const float* __restrict__ in, const float* __restrict__ w,
                          const float* __restrict__ bias, float* __restrict__ out)
{
    int p = blockIdx.x*256 + threadIdx.x;
    int b = blockIdx.y;
    const float* inb = in + (size_t)b*CIN*HW + p;
    float acc[COUT];
#pragma unroll
    for(int o=0;o<COUT;o++) acc[o] = bias ? bias[o] : 0.f;
    for(int c=0;c<CIN;c++){
        float v = inb[(size_t)c*HW];
#pragma unroll
        for(int o=0;o<COUT;o++) acc[o] += w[o*CIN+c]*v;
    }
    float* ob = out + (size_t)b*COUT*HW + p;
#pragma unroll
    for(int o=0;o<COUT;o++) ob[(size_t)o*HW] = acc[o];
}

// ---------------- generic direct 3x3 conv, zero pad = dil, optional fused input ops ----
// in_val = (in[idx] + (add_in?add_in[idx]:0)) * (scale_c?scale_c[b,c]:1) * (scale_p?scale_p[b,pix]:1)
template<int CIN,int COUT>
__global__ void conv3x3_k(const float* __restrict__ in, const float* __restrict__ add_in,
                          const float* __restrict__ w, const float* __restrict__ bias,
                          const float* __restrict__ scale_c, const float* __restrict__ scale_p,
                          float* __restrict__ out, int dil)
{
    int tx = threadIdx.x & 15, ty = threadIdx.x >> 4;
    int j = blockIdx.x*16 + tx;
    int i = blockIdx.y*16 + ty;
    int b = blockIdx.z;
    const float* inb  = in + (size_t)b*CIN*HW;
    const float* addb = add_in ? add_in + (size_t)b*CIN*HW : nullptr;
    const float* scb  = scale_c ? scale_c + b*CIN : nullptr;
    const float* spb  = scale_p ? scale_p + (size_t)b*HW : nullptr;
    float acc[COUT];
#pragma unroll
    for(int o=0;o<COUT;o++) acc[o] = bias ? bias[o] : 0.f;
    for(int c=0;c<CIN;c++){
        float sc = scb ? scb[c] : 1.f;
#pragma unroll
        for(int kh=0;kh<3;kh++){
            int ii = i + (kh-1)*dil;
            if (ii < 0 || ii >= Hd) continue;
#pragma unroll
            for(int kw=0;kw<3;kw++){
                int jj = j + (kw-1)*dil;
                if (jj < 0 || jj >= Wd) continue;
                size_t idx = (size_t)c*HW + ii*Wd + jj;
                float v = inb[idx];
                if (addb) v += addb[idx];
                if (scb)  v *= sc;
                if (spb)  v *= spb[ii*Wd+jj];
                int n = kh*3+kw;
#pragma unroll
                for(int o=0;o<COUT;o++) acc[o] += w[(o*CIN+c)*9 + n] * v;
            }
        }
    }
    float* ob = out + (size_t)b*COUT*HW + i*Wd + j;
#pragma unroll
    for(int o=0;o<COUT;o++) ob[(size_t)o*HW] = acc[o];
}

// ---------------- BN stats: one block per channel, double accumulation ----------------
__global__ void bn_stats_k(const float* __restrict__ x, int C, float* __restrict__ mr)
{
    int c = blockIdx.x;
    int tid = threadIdx.x;
    double s = 0.0, s2 = 0.0;
    for(int b=0;b<Bn;b++){
        const float* p = x + ((size_t)b*C + c)*HW;
        for(int idx=tid; idx<HW; idx+=256){
            double v = (double)p[idx];
            s += v; s2 += v*v;
        }
    }
    __shared__ double sh[512];
    sh[tid] = s; sh[256+tid] = s2;
    __syncthreads();
    for(int o=128;o>0;o>>=1){
        if (tid < o){ sh[tid] += sh[tid+o]; sh[256+tid] += sh[256+tid+o]; }
        __syncthreads();
    }
    if (tid==0){
        double n = (double)Bn*HW;
        double m = sh[0]/n;
        double var = sh[256]/n - m*m;
        mr[c]   = (float)m;
        mr[C+c] = rsqrtf((float)var + 1e-5f);
    }
}

// ---------------- BN apply (+optional extras e1,e2 with batch stride, +relu) ----------
__global__ void bn_apply_k(const float* __restrict__ x, const float* __restrict__ mr, int C,
                           const float* __restrict__ e1, long long e1_bs,
                           const float* __restrict__ e2, long long e2_bs,
                           float* __restrict__ out, int relu)
{
    int p = blockIdx.x*256 + threadIdx.x;
    int c = blockIdx.y, b = blockIdx.z;
    size_t idx = ((size_t)b*C + c)*HW + p;
    float v = (x[idx] - mr[c]) * mr[C+c];
    if (e1) v += e1[(size_t)b*e1_bs + (size_t)c*HW + p];
    if (e2) v += e2[(size_t)b*e2_bs + (size_t)c*HW + p];
    if (relu) v = fmaxf(v, 0.f);
    out[idx] = v;
}

// ---------------- channel concat helpers ----------------
__global__ void cat2_k(const float* __restrict__ a, long long a_bs,
                       const float* __restrict__ hfp, float* __restrict__ out)
{
    int p = blockIdx.x*256 + threadIdx.x;
    int c = blockIdx.y, b = blockIdx.z;
    float v = (c < 16) ? a[(size_t)b*a_bs + (size_t)c*HW + p]
                       : hfp[((size_t)b*16 + (c-16))*HW + p];
    out[((size_t)b*32 + c)*HW + p] = v;
}

__global__ void cat4_k(const float* __restrict__ x0, const float* __restrict__ x1,
                       const float* __restrict__ x2, const float* __restrict__ x3,
                       float* __restrict__ out)
{
    int p = blockIdx.x*256 + threadIdx.x;
    int c = blockIdx.y, b = blockIdx.z;
    const float* src = (c<16)? x0 : (c<32)? x1 : (c<48)? x2 : x3;
    out[((size_t)b*64 + c)*HW + p] = src[((size_t)b*16 + (c&15))*HW + p];
}

// ---------------- deformable conv: thread per pixel, 16 in ch -> 16 out ch -------------
// Exact reference boundary semantics: padded coords, mask->snap-to-floor->clamp.
__global__ void deform_k(const float* __restrict__ t, const float* __restrict__ off,
                         const float* __restrict__ w, float* __restrict__ out)
{
    int tx = threadIdx.x & 15, ty = threadIdx.x >> 4;
    int j = blockIdx.x*16 + tx;
    int i = blockIdx.y*16 + ty;
    int b = blockIdx.z;
    const float* tb = t + (size_t)b*16*HW;
    const float* ob = off + (size_t)b*18*HW + i*Wd + j;
    float acc[16];
#pragma unroll
    for(int o=0;o<16;o++) acc[o] = 0.f;

    for(int n=0;n<9;n++){
        float offx = ob[(size_t)(2*n)*HW];
        float offy = ob[(size_t)(2*n+1)*HW];
        // p_0 + p_n: px0 = (i+1)+(n/3-1) = i + n/3 ; py0 = j + n%3  (padded coords)
        float px = (float)(i + n/3) + offx;
        float py = (float)(j + n%3) + offy;
        float flx = floorf(px), fly = floorf(py);
        float qltx = fminf(fmaxf(flx,       0.f), 257.f);
        float qlty = fminf(fmaxf(fly,       0.f), 257.f);
        float qrbx = fminf(fmaxf(flx + 1.f, 0.f), 257.f);
        float qrby = fminf(fmaxf(fly + 1.f, 0.f), 257.f);
        // mask: outside [padding, Hp-1-padding] = [1, 256] -> snap p to floor(p)
        if (px < 1.f || px > 256.f) px = flx;
        if (py < 1.f || py > 256.f) py = fly;
        px = fminf(fmaxf(px, 0.f), 257.f);
        py = fminf(fmaxf(py, 0.f), 257.f);
        float wx_lt = 1.f + (qltx - px);
        float wx_rb = 1.f - (qrbx - px);
        float wy_lt = 1.f + (qlty - py);
        float wy_rb = 1.f - (qrby - py);
        float glt = wx_lt*wy_lt, grb = wx_rb*wy_rb, glb = wx_lt*wy_rb, grt = wx_rb*wy_lt;
        // padded coord a -> unpadded a-1, valid iff 1<=a<=256 (zero pad ring of 1)
        int ix0 = (int)qltx - 1, iy0 = (int)qlty - 1;
        int ix1 = (int)qrbx - 1, iy1 = (int)qrby - 1;
        bool vx0 = (ix0>=0 && ix0<Hd), vx1 = (ix1>=0 && ix1<Hd);
        bool vy0 = (iy0>=0 && iy0<Wd), vy1 = (iy1>=0 && iy1<Wd);
        int i00 = ix0*Wd+iy0, i01 = ix0*Wd+iy1, i10 = ix1*Wd+iy0, i11 = ix1*Wd+iy1;
        float vals[16];
#pragma unroll
        for(int c=0;c<16;c++){
            const float* tc = tb + (size_t)c*HW;
            float v00 = (vx0&&vy0) ? tc[i00] : 0.f;
            float v11 = (vx1&&vy1) ? tc[i11] : 0.f;
            float v01 = (vx0&&vy1) ? tc[i01] : 0.f;
            float v10 = (vx1&&vy0) ? tc[i10] : 0.f;
            vals[c] = glt*v00 + grb*v11 + glb*v01 + grt*v10;
        }
#pragma unroll
        for(int o=0;o<16;o++){
            float a = acc[o];
#pragma unroll
            for(int c=0;c<16;c++) a += w[(o*16+c)*9 + n] * vals[c];
            acc[o] = a;
        }
    }
    float* outb = out + (size_t)b*16*HW + i*Wd + j;
#pragma unroll
    for(int o=0;o<16;o++) outb[(size_t)o*HW] = acc[o];
}

// ---------------- CBAM pieces ----------------
__global__ void pool_k(const float* __restrict__ x, float* __restrict__ pavg, float* __restrict__ pmax)
{
    int bc = blockIdx.x;   // b*64 + c
    int tid = threadIdx.x;
    const float* p = x + (size_t)bc*HW;
    float s = 0.f, mx = -1e30f;
    for(int i=tid;i<HW;i+=256){ float v = p[i]; s += v; mx = fmaxf(mx, v); }
    __shared__ float sh[512];
    sh[tid] = s; sh[256+tid] = mx;
    __syncthreads();
    for(int o=128;o>0;o>>=1){
        if (tid < o){ sh[tid] += sh[tid+o]; sh[256+tid] = fmaxf(sh[256+tid], sh[256+tid+o]); }
        __syncthreads();
    }
    if (tid==0){ pavg[bc] = sh[0] / (float)HW; pmax[bc] = sh[256]; }
}

__global__ void ca_k(const float* __restrict__ pavg, const float* __restrict__ pmax,
                     const float* __restrict__ w1, const float* __restrict__ w2,
                     float* __restrict__ ca)
{
    int b = blockIdx.x;
    int tid = threadIdx.x;   // 64 threads
    __shared__ float ha[4], hm[4];
    if (tid < 4){
        float sa = 0.f, sm = 0.f;
        for(int c=0;c<64;c++){
            sa += w1[tid*64+c] * pavg[b*64+c];
            sm += w1[tid*64+c] * pmax[b*64+c];
        }
        ha[tid] = fmaxf(sa, 0.f);
        hm[tid] = fmaxf(sm, 0.f);
    }
    __syncthreads();
    float s = 0.f;
    for(int h=0;h<4;h++) s += w2[tid*4+h] * (ha[h] + hm[h]);
    ca[b*64+tid] = 1.f / (1.f + expf(-s));
}

__global__ void spstats_k(const float* __restrict__ x, const float* __restrict__ ca,
                          float* __restrict__ spm, float* __restrict__ spx)
{
    int p = blockIdx.x*256 + threadIdx.x;
    int b = blockIdx.y;
    const float* xb = x + (size_t)b*64*HW + p;
    const float* cb = ca + b*64;
    float s = 0.f, mx = -1e30f;
    for(int c=0;c<64;c++){
        float v = xb[(size_t)c*HW] * cb[c];
        s += v; mx = fmaxf(mx, v);
    }
    spm[(size_t)b*HW+p] = s * (1.f/64.f);
    spx[(size_t)b*HW+p] = mx;
}

__global__ void spconv_k(const float* __restrict__ spm, const float* __restrict__ spx,
                         const float* __restrict__ wsp, float* __restrict__ sa)
{
    int tx = threadIdx.x & 15, ty = threadIdx.x >> 4;
    int j = blockIdx.x*16 + tx;
    int i = blockIdx.y*16 + ty;
    int b = blockIdx.z;
    const float* m = spm + (size_t)b*HW;
    const float* x = spx + (size_t)b*HW;
    float s = 0.f;
    for(int kh=0;kh<7;kh++){
        int ii = i + kh - 3; if (ii<0||ii>=Hd) continue;
        for(int kw=0;kw<7;kw++){
            int jj = j + kw - 3; if (jj<0||jj>=Wd) continue;
            s += wsp[kh*7+kw]*m[ii*Wd+jj] + wsp[49+kh*7+kw]*x[ii*Wd+jj];
        }
    }
    sa[(size_t)b*HW + i*Wd + j] = 1.f / (1.f + expf(-s));
}

// ---------------- orchestration ----------------
extern "C" void kernel_launch(void* const* d_in, const int* in_sizes, int n_in,
                              void* d_out, int out_size, void* d_ws, size_t ws_size,
                              hipStream_t stream)
{
    const float* lf        = (const float*)d_in[0];
    const float* hf        = (const float*)d_in[1];
    const float* w_conv1_1 = (const float*)d_in[2];
    const float* b_conv1_1 = (const float*)d_in[3];
    const float* w_conv    = (const float*)d_in[4];
    const float* w_offset  = (const float*)d_in[5];
    const float* b_offset  = (const float*)d_in[6];
    const float* w_deform  = (const float*)d_in[7];
    const float* w_dil[4]  = {(const float*)d_in[8],(const float*)d_in[9],
                              (const float*)d_in[10],(const float*)d_in[11]};
    const float* w_conv1   = (const float*)d_in[12];
    const float* w_conv2   = (const float*)d_in[13];
    const float* w_fc1     = (const float*)d_in[14];
    const float* w_fc2     = (const float*)d_in[15];
    const float* w_sp      = (const float*)d_in[16];
    const float* w_conv1_2 = (const float*)d_in[17];
    const float* b_conv1_2 = (const float*)d_in[18];
    const float* w_conv3_3 = (const float*)d_in[19];
    float* out = (float*)d_out;

    float* ws = (float*)d_ws;
    size_t off_f = 0;
    auto alloc = [&](size_t n){ float* p = ws + off_f; off_f += n; return p; };
    const size_t S16 = (size_t)Bn*16*HW;

    float* hf_p  = alloc(S16);            // persistent (all branches)
    float* B16_0 = alloc(S16);            // xb / t
    float* B16_1 = alloc(S16);            // d0 (deform out) / conv2 pre-bn
    float* B16_2 = alloc(S16);            // d1 (dil conv, bn in place)
    float* B32   = B16_1;                 // cat2 buffer aliases B16_1+B16_2 (dead there)
    float* B64F  = ws;                    // final-stage 64ch buffer aliases first 4 S16 bufs
    float* Boff  = alloc((size_t)Bn*18*HW);
    float* B64_0 = alloc((size_t)Bn*64*HW); // d2 / xx
    float* xk[4] = {alloc(S16),alloc(S16),alloc(S16),alloc(S16)};
    float* spm   = alloc((size_t)Bn*HW);
    float* spx   = alloc((size_t)Bn*HW);
    float* sa    = alloc((size_t)Bn*HW);
    float* mr    = alloc(128);
    float* pavg  = alloc(256);
    float* pmax  = alloc(256);
    float* ca    = alloc(256);
    (void)ws_size; (void)in_sizes; (void)n_in; (void)out_size;

    dim3 blk(256);
    dim3 gpix(HW/256, Bn);
    dim3 gtile(16,16,Bn);
    const long long bs16 = 16LL*HW, bs64 = 64LL*HW;

    // Stage A: hf_p = relu(bn(conv1x1(hf)))
    conv1x1_k<64,16><<<gpix,blk,0,stream>>>(hf, w_conv1_1, b_conv1_1, hf_p);
    bn_stats_k<<<16,blk,0,stream>>>(hf_p, 16, mr);
    bn_apply_k<<<dim3(256,16,Bn),blk,0,stream>>>(hf_p, mr, 16, nullptr,0, nullptr,0, hf_p, 1);

    // Branches
    for(int k=0;k<4;k++){
        const float* prev; long long prev_bs;
        if (k==0){ prev = lf;      prev_bs = bs64; }
        else     { prev = xk[k-1]; prev_bs = bs16; }
        cat2_k<<<dim3(256,32,Bn),blk,0,stream>>>(prev, prev_bs, hf_p, B32);
        conv3x3_k<32,16><<<gtile,blk,0,stream>>>(B32, nullptr, w_conv, nullptr, nullptr, nullptr, B16_0, 1);
        bn_stats_k<<<16,blk,0,stream>>>(B16_0, 16, mr);
        const float* e1; long long e1bs; const float* e2 = nullptr; long long e2bs = 0;
        if (k==0){ e1 = lf + 16*HW; e1bs = bs64; }
        else if (k==3){ e1 = xk[2]; e1bs = bs16; }
        else { e1 = xk[k-1]; e1bs = bs16; e2 = lf + (size_t)(k+1)*16*HW; e2bs = bs64; }
        bn_apply_k<<<dim3(256,16,Bn),blk,0,stream>>>(B16_0, mr, 16, e1,e1bs, e2,e2bs, B16_0, 0); // t
        conv3x3_k<16,18><<<gtile,blk,0,stream>>>(B16_0, nullptr, w_offset, b_offset, nullptr, nullptr, Boff, 1);
        deform_k<<<gtile,blk,0,stream>>>(B16_0, Boff, w_deform, B16_1);
        conv3x3_k<16,16><<<gtile,blk,0,stream>>>(B16_1, nullptr, w_dil[k], nullptr, nullptr, nullptr, B16_2, k+1);
        bn_stats_k<<<16,blk,0,stream>>>(B16_2, 16, mr);
        bn_apply_k<<<dim3(256,16,Bn),blk,0,stream>>>(B16_2, mr, 16, nullptr,0, nullptr,0, B16_2, 0);
        conv3x3_k<16,64><<<gtile,blk,0,stream>>>(B16_2, nullptr, w_conv1, nullptr, nullptr, nullptr, B64_0, 1);
        bn_stats_k<<<64,blk,0,stream>>>(B64_0, 64, mr);
        bn_apply_k<<<dim3(256,64,Bn),blk,0,stream>>>(B64_0, mr, 64, nullptr,0, nullptr,0, B64_0, 0);
        // CBAM
        pool_k<<<Bn*64,blk,0,stream>>>(B64_0, pavg, pmax);
        ca_k<<<Bn,dim3(64),0,stream>>>(pavg, pmax, w_fc1, w_fc2, ca);
        spstats_k<<<dim3(256,Bn),blk,0,stream>>>(B64_0, ca, spm, spx);
        spconv_k<<<gtile,blk,0,stream>>>(spm, spx, w_sp, sa);
        // conv2 with fused input scaling by ca (per-channel) and sa (per-pixel)
        conv3x3_k<64,16><<<gtile,blk,0,stream>>>(B64_0, nullptr, w_conv2, nullptr, ca, sa, B16_1, 1);
        bn_stats_k<<<16,blk,0,stream>>>(B16_1, 16, mr);
        bn_apply_k<<<dim3(256,16,Bn),blk,0,stream>>>(B16_1, mr, 16, nullptr,0, nullptr,0, xk[k], 0);
    }

    // Final: xx = relu(bn(conv1x1(cat4))), out = bn(conv3x3(lf + xx))
    cat4_k<<<dim3(256,64,Bn),blk,0,stream>>>(xk[0], xk[1], xk[2], xk[3], B64F);
    conv1x1_k<64,64><<<gpix,blk,0,stream>>>(B64F, w_conv1_2, b_conv1_2, B64_0);
    bn_stats_k<<<64,blk,0,stream>>>(B64_0, 64, mr);
    bn_apply_k<<<dim3(256,64,Bn),blk,0,stream>>>(B64_0, mr, 64, nullptr,0, nullptr,0, B64_0, 1); // xx
    conv3x3_k<64,64><<<gtile,blk,0,stream>>>(lf, B64_0, w_conv3_3, nullptr, nullptr, nullptr, B64F, 1);
    bn_stats_k<<<64,blk,0,stream>>>(B64F, 64, mr);
    bn_apply_k<<<dim3(256,64,Bn),blk,0,stream>>>(B64F, mr, 64, nullptr,0, nullptr,0, out, 0);
}

// Round 2
// 4300.715 us; speedup vs baseline: 2.8213x; 2.8213x over previous
//
#include <hip/hip_runtime.h>
#include <math.h>

#define HW 65536
#define Wd 256
#define Hd 256
#define Bn 4
#define NS 16   // bn_stats splits per channel

// ================= vectorized direct 3x3 conv =================
// Each thread computes 4 horizontally-consecutive pixels for COB output chans.
// Tile: 64 wide (16 thr * 4px) x 16 rows. Grid: (4, 16*(COUT/COB), Bn).
// Input = concat(inA[CIN1], inB[CIN2]) along channels (inB may be null if CIN2==0).
// Fused input ops: v = (inA + add) * scale_c[b,c] * scale_p[b,pix]
template<int CIN1,int CIN2,int COUT,int COB,int DIL>
__global__ __launch_bounds__(256) void conv3_k(
    const float* __restrict__ inA, long long a_bs,
    const float* __restrict__ inB,
    const float* __restrict__ add_in,
    const float* __restrict__ w, const float* __restrict__ bias,
    const float* __restrict__ scale_c, const float* __restrict__ scale_p,
    float* __restrict__ out)
{
    constexpr int CIN = CIN1 + CIN2;
    constexpr int SP = 2*DIL + 4;
    int tx = threadIdx.x & 15, ty = threadIdx.x >> 4;
    int j0 = blockIdx.x*64 + tx*4;
    int iy = blockIdx.y & 15;
    int chunk = blockIdx.y >> 4;
    int i = iy*16 + ty;
    int b = blockIdx.z;
    int o0 = chunk*COB;

    float acc[COB][4];
#pragma unroll
    for(int o=0;o<COB;o++){
        float bv = bias ? bias[o0+o] : 0.f;
#pragma unroll
        for(int q=0;q<4;q++) acc[o][q] = bv;
    }

    const float* spb = scale_p ? scale_p + (size_t)b*HW : nullptr;

    for(int c=0;c<CIN;c++){
        const float* cb;
        if (CIN2 == 0 || c < CIN1) cb = inA + (size_t)b*a_bs + (size_t)c*HW;
        else                       cb = inB + ((size_t)b*CIN2 + (c-CIN1))*HW;
        const float* ab = add_in ? add_in + (size_t)b*a_bs + (size_t)c*HW : nullptr;
        float sc = scale_c ? scale_c[b*CIN + c] : 1.f;

        float r[3][SP];
#pragma unroll
        for(int kh=0;kh<3;kh++){
#pragma unroll
            for(int t=0;t<SP;t++) r[kh][t] = 0.f;
            int ii = i + (kh-1)*DIL;
            if (ii < 0 || ii >= Hd) continue;
            const float* row = cb + ii*Wd;
            float4 c4 = *(const float4*)(row + j0);
            r[kh][DIL+0]=c4.x; r[kh][DIL+1]=c4.y; r[kh][DIL+2]=c4.z; r[kh][DIL+3]=c4.w;
#pragma unroll
            for(int t=0;t<DIL;t++){
                int jl = j0 - DIL + t;
                if (jl >= 0) r[kh][t] = row[jl];
                int jr = j0 + 4 + t;
                if (jr < Wd) r[kh][DIL+4+t] = row[jr];
            }
            if (ab){
                const float* arow = ab + ii*Wd;
                float4 a4 = *(const float4*)(arow + j0);
                r[kh][DIL+0]+=a4.x; r[kh][DIL+1]+=a4.y; r[kh][DIL+2]+=a4.z; r[kh][DIL+3]+=a4.w;
#pragma unroll
                for(int t=0;t<DIL;t++){
                    int jl = j0 - DIL + t;
                    if (jl >= 0) r[kh][t] += arow[jl];
                    int jr = j0 + 4 + t;
                    if (jr < Wd) r[kh][DIL+4+t] += arow[jr];
                }
            }
            if (spb){
                const float* srow = spb + ii*Wd;
                float4 s4 = *(const float4*)(srow + j0);
                r[kh][DIL+0]*=s4.x; r[kh][DIL+1]*=s4.y; r[kh][DIL+2]*=s4.z; r[kh][DIL+3]*=s4.w;
#pragma unroll
                for(int t=0;t<DIL;t++){
                    int jl = j0 - DIL + t;
                    if (jl >= 0) r[kh][t] *= srow[jl];
                    int jr = j0 + 4 + t;
                    if (jr < Wd) r[kh][DIL+4+t] *= srow[jr];
                }
            }
            if (scale_c){
#pragma unroll
                for(int t=0;t<SP;t++) r[kh][t] *= sc;
            }
        }

#pragma unroll
        for(int o=0;o<COB;o++){
#pragma unroll
            for(int kh=0;kh<3;kh++){
#pragma unroll
                for(int kw=0;kw<3;kw++){
                    float ww = w[((size_t)(o0+o)*CIN + c)*9 + kh*3 + kw];
#pragma unroll
                    for(int q=0;q<4;q++)
                        acc[o][q] = fmaf(ww, r[kh][kw*DIL + q], acc[o][q]);
                }
            }
        }
    }

    float* ob = out + ((size_t)b*COUT + o0)*HW + i*Wd + j0;
#pragma unroll
    for(int o=0;o<COB;o++){
        float4 v; v.x=acc[o][0]; v.y=acc[o][1]; v.z=acc[o][2]; v.w=acc[o][3];
        *(float4*)(ob + (size_t)o*HW) = v;
    }
}

// ================= conv 1x1 : thread per pixel, all COUT channels =================
template<int CIN,int COUT>
__global__ void conv1x1_k(const float* __restrict__ in, const float* __restrict__ w,
                          const float* __restrict__ bias, float* __restrict__ out)
{
    int p = blockIdx.x*256 + threadIdx.x;
    int b = blockIdx.y;
    const float* inb = in + (size_t)b*CIN*HW + p;
    float acc[COUT];
#pragma unroll
    for(int o=0;o<COUT;o++) acc[o] = bias ? bias[o] : 0.f;
    for(int c=0;c<CIN;c++){
        float v = inb[(size_t)c*HW];
#pragma unroll
        for(int o=0;o<COUT;o++) acc[o] += w[o*CIN+c]*v;
    }
    float* ob = out + (size_t)b*COUT*HW + p;
#pragma unroll
    for(int o=0;o<COUT;o++) ob[(size_t)o*HW] = acc[o];
}

// ================= BN stats: split partials + finalize =================
__global__ void bn_stats_part(const float* __restrict__ x, int C, double* __restrict__ part)
{
    int c = blockIdx.x, s = blockIdx.y, tid = threadIdx.x;
    double sum = 0.0, sum2 = 0.0;
    for(int t=0;t<64;t++){
        int g = s*16384 + t*256 + tid;    // g in [0, Bn*HW)
        int b = g >> 16, p = g & 65535;
        double v = (double)x[((size_t)b*C + c)*HW + p];
        sum += v; sum2 += v*v;
    }
    __shared__ double sh[512];
    sh[tid] = sum; sh[256+tid] = sum2;
    __syncthreads();
    for(int o=128;o>0;o>>=1){
        if (tid < o){ sh[tid] += sh[tid+o]; sh[256+tid] += sh[256+tid+o]; }
        __syncthreads();
    }
    if (tid==0){ part[(c*NS+s)*2] = sh[0]; part[(c*NS+s)*2+1] = sh[256]; }
}

__global__ void bn_finalize(const double* __restrict__ part, int C, float* __restrict__ mr)
{
    int c = threadIdx.x;
    if (c >= C) return;
    double s = 0.0, s2 = 0.0;
    for(int k=0;k<NS;k++){ s += part[(c*NS+k)*2]; s2 += part[(c*NS+k)*2+1]; }
    double n = (double)Bn*HW;
    double m = s/n;
    double var = s2/n - m*m;
    mr[c]   = (float)m;
    mr[C+c] = rsqrtf((float)var + 1e-5f);
}

// ================= BN apply, float4 (+extras with batch stride, +relu) =================
__global__ void bn_apply_k(const float* __restrict__ x, const float* __restrict__ mr, int C,
                           const float* __restrict__ e1, long long e1_bs,
                           const float* __restrict__ e2, long long e2_bs,
                           float* __restrict__ out, int relu)
{
    int p = (blockIdx.x*256 + threadIdx.x)*4;
    int c = blockIdx.y, b = blockIdx.z;
    size_t idx = ((size_t)b*C + c)*HW + p;
    float m = mr[c], r = mr[C+c];
    float4 v = *(const float4*)(x + idx);
    v.x = (v.x-m)*r; v.y = (v.y-m)*r; v.z = (v.z-m)*r; v.w = (v.w-m)*r;
    if (e1){
        float4 a = *(const float4*)(e1 + (size_t)b*e1_bs + (size_t)c*HW + p);
        v.x+=a.x; v.y+=a.y; v.z+=a.z; v.w+=a.w;
    }
    if (e2){
        float4 a = *(const float4*)(e2 + (size_t)b*e2_bs + (size_t)c*HW + p);
        v.x+=a.x; v.y+=a.y; v.z+=a.z; v.w+=a.w;
    }
    if (relu){
        v.x=fmaxf(v.x,0.f); v.y=fmaxf(v.y,0.f); v.z=fmaxf(v.z,0.f); v.w=fmaxf(v.w,0.f);
    }
    *(float4*)(out + idx) = v;
}

// ================= channel concat (4x16 -> 64) =================
__global__ void cat4_k(const float* __restrict__ x0, const float* __restrict__ x1,
                       const float* __restrict__ x2, const float* __restrict__ x3,
                       float* __restrict__ out)
{
    int p = (blockIdx.x*256 + threadIdx.x)*4;
    int c = blockIdx.y, b = blockIdx.z;
    const float* src = (c<16)? x0 : (c<32)? x1 : (c<48)? x2 : x3;
    *(float4*)(out + ((size_t)b*64 + c)*HW + p) =
        *(const float4*)(src + ((size_t)b*16 + (c&15))*HW + p);
}

// ================= deformable conv (exact reference boundary semantics) ============
__global__ void deform_k(const float* __restrict__ t, const float* __restrict__ off,
                         const float* __restrict__ w, float* __restrict__ out)
{
    int tx = threadIdx.x & 15, ty = threadIdx.x >> 4;
    int j = blockIdx.x*16 + tx;
    int i = blockIdx.y*16 + ty;
    int b = blockIdx.z;
    const float* tb = t + (size_t)b*16*HW;
    const float* ob = off + (size_t)b*18*HW + i*Wd + j;
    float acc[16];
#pragma unroll
    for(int o=0;o<16;o++) acc[o] = 0.f;

    for(int n=0;n<9;n++){
        float offx = ob[(size_t)(2*n)*HW];
        float offy = ob[(size_t)(2*n+1)*HW];
        float px = (float)(i + n/3) + offx;
        float py = (float)(j + n%3) + offy;
        float flx = floorf(px), fly = floorf(py);
        float qltx = fminf(fmaxf(flx,       0.f), 257.f);
        float qlty = fminf(fmaxf(fly,       0.f), 257.f);
        float qrbx = fminf(fmaxf(flx + 1.f, 0.f), 257.f);
        float qrby = fminf(fmaxf(fly + 1.f, 0.f), 257.f);
        if (px < 1.f || px > 256.f) px = flx;
        if (py < 1.f || py > 256.f) py = fly;
        px = fminf(fmaxf(px, 0.f), 257.f);
        py = fminf(fmaxf(py, 0.f), 257.f);
        float wx_lt = 1.f + (qltx - px);
        float wx_rb = 1.f - (qrbx - px);
        float wy_lt = 1.f + (qlty - py);
        float wy_rb = 1.f - (qrby - py);
        float glt = wx_lt*wy_lt, grb = wx_rb*wy_rb, glb = wx_lt*wy_rb, grt = wx_rb*wy_lt;
        int ix0 = (int)qltx - 1, iy0 = (int)qlty - 1;
        int ix1 = (int)qrbx - 1, iy1 = (int)qrby - 1;
        bool vx0 = (ix0>=0 && ix0<Hd), vx1 = (ix1>=0 && ix1<Hd);
        bool vy0 = (iy0>=0 && iy0<Wd), vy1 = (iy1>=0 && iy1<Wd);
        int i00 = ix0*Wd+iy0, i01 = ix0*Wd+iy1, i10 = ix1*Wd+iy0, i11 = ix1*Wd+iy1;
        float vals[16];
#pragma unroll
        for(int c=0;c<16;c++){
            const float* tc = tb + (size_t)c*HW;
            float v00 = (vx0&&vy0) ? tc[i00] : 0.f;
            float v11 = (vx1&&vy1) ? tc[i11] : 0.f;
            float v01 = (vx0&&vy1) ? tc[i01] : 0.f;
            float v10 = (vx1&&vy0) ? tc[i10] : 0.f;
            vals[c] = glt*v00 + grb*v11 + glb*v01 + grt*v10;
        }
#pragma unroll
        for(int o=0;o<16;o++){
            float a = acc[o];
#pragma unroll
            for(int c=0;c<16;c++) a += w[(o*16+c)*9 + n] * vals[c];
            acc[o] = a;
        }
    }
    float* outb = out + (size_t)b*16*HW + i*Wd + j;
#pragma unroll
    for(int o=0;o<16;o++) outb[(size_t)o*HW] = acc[o];
}

// ================= CBAM pieces =================
__global__ void pool_k(const float* __restrict__ x, float* __restrict__ pavg, float* __restrict__ pmax)
{
    int bc = blockIdx.x;
    int tid = threadIdx.x;
    const float* p = x + (size_t)bc*HW;
    float s = 0.f, mx = -1e30f;
    for(int i=tid;i<HW;i+=256){ float v = p[i]; s += v; mx = fmaxf(mx, v); }
    __shared__ float sh[512];
    sh[tid] = s; sh[256+tid] = mx;
    __syncthreads();
    for(int o=128;o>0;o>>=1){
        if (tid < o){ sh[tid] += sh[tid+o]; sh[256+tid] = fmaxf(sh[256+tid], sh[256+tid+o]); }
        __syncthreads();
    }
    if (tid==0){ pavg[bc] = sh[0] / (float)HW; pmax[bc] = sh[256]; }
}

__global__ void ca_k(const float* __restrict__ pavg, const float* __restrict__ pmax,
                     const float* __restrict__ w1, const float* __restrict__ w2,
                     float* __restrict__ ca)
{
    int b = blockIdx.x;
    int tid = threadIdx.x;   // 64 threads
    __shared__ float ha[4], hm[4];
    if (tid < 4){
        float sa = 0.f, sm = 0.f;
        for(int c=0;c<64;c++){
            sa += w1[tid*64+c] * pavg[b*64+c];
            sm += w1[tid*64+c] * pmax[b*64+c];
        }
        ha[tid] = fmaxf(sa, 0.f);
        hm[tid] = fmaxf(sm, 0.f);
    }
    __syncthreads();
    float s = 0.f;
    for(int h=0;h<4;h++) s += w2[tid*4+h] * (ha[h] + hm[h]);
    ca[b*64+tid] = 1.f / (1.f + expf(-s));
}

__global__ void spstats_k(const float* __restrict__ x, const float* __restrict__ ca,
                          float* __restrict__ spm, float* __restrict__ spx)
{
    int p = blockIdx.x*256 + threadIdx.x;
    int b = blockIdx.y;
    const float* xb = x + (size_t)b*64*HW + p;
    const float* cb = ca + b*64;
    float s = 0.f, mx = -1e30f;
    for(int c=0;c<64;c++){
        float v = xb[(size_t)c*HW] * cb[c];
        s += v; mx = fmaxf(mx, v);
    }
    spm[(size_t)b*HW+p] = s * (1.f/64.f);
    spx[(size_t)b*HW+p] = mx;
}

__global__ void spconv_k(const float* __restrict__ spm, const float* __restrict__ spx,
                         const float* __restrict__ wsp, float* __restrict__ sa)
{
    int tx = threadIdx.x & 15, ty = threadIdx.x >> 4;
    int j = blockIdx.x*16 + tx;
    int i = blockIdx.y*16 + ty;
    int b = blockIdx.z;
    const float* m = spm + (size_t)b*HW;
    const float* x = spx + (size_t)b*HW;
    float s = 0.f;
    for(int kh=0;kh<7;kh++){
        int ii = i + kh - 3; if (ii<0||ii>=Hd) continue;
        for(int kw=0;kw<7;kw++){
            int jj = j + kw - 3; if (jj<0||jj>=Wd) continue;
            s += wsp[kh*7+kw]*m[ii*Wd+jj] + wsp[49+kh*7+kw]*x[ii*Wd+jj];
        }
    }
    sa[(size_t)b*HW + i*Wd + j] = 1.f / (1.f + expf(-s));
}

// ================= orchestration =================
extern "C" void kernel_launch(void* const* d_in, const int* in_sizes, int n_in,
                              void* d_out, int out_size, void* d_ws, size_t ws_size,
                              hipStream_t stream)
{
    const float* lf        = (const float*)d_in[0];
    const float* hf        = (const float*)d_in[1];
    const float* w_conv1_1 = (const float*)d_in[2];
    const float* b_conv1_1 = (const float*)d_in[3];
    const float* w_conv    = (const float*)d_in[4];
    const float* w_offset  = (const float*)d_in[5];
    const float* b_offset  = (const float*)d_in[6];
    const float* w_deform  = (const float*)d_in[7];
    const float* w_dil[4]  = {(const float*)d_in[8],(const float*)d_in[9],
                              (const float*)d_in[10],(const float*)d_in[11]};
    const float* w_conv1   = (const float*)d_in[12];
    const float* w_conv2   = (const float*)d_in[13];
    const float* w_fc1     = (const float*)d_in[14];
    const float* w_fc2     = (const float*)d_in[15];
    const float* w_sp      = (const float*)d_in[16];
    const float* w_conv1_2 = (const float*)d_in[17];
    const float* b_conv1_2 = (const float*)d_in[18];
    const float* w_conv3_3 = (const float*)d_in[19];
    float* out = (float*)d_out;

    float* ws = (float*)d_ws;
    size_t off_f = 0;
    auto alloc = [&](size_t n){ float* p = ws + off_f; off_f += n; return p; };
    const size_t S16 = (size_t)Bn*16*HW;

    float* hf_p  = alloc(S16);
    float* B16_0 = alloc(S16);              // t
    float* B16_1 = alloc(S16);              // deform out / conv2 pre-bn
    float* B16_2 = alloc(S16);              // dil conv out
    float* B64F  = ws;                      // final 64ch buffer aliases first 4 S16 bufs
    float* Boff  = alloc((size_t)Bn*18*HW);
    float* B64_0 = alloc((size_t)Bn*64*HW); // d2 / xx
    float* xk[4] = {alloc(S16),alloc(S16),alloc(S16),alloc(S16)};
    float* spm   = alloc((size_t)Bn*HW);
    float* spx   = alloc((size_t)Bn*HW);
    float* sa    = alloc((size_t)Bn*HW);
    float* mr    = alloc(128);
    float* pavg  = alloc(256);
    float* pmax  = alloc(256);
    float* ca    = alloc(256);
    double* part = (double*)alloc(64*NS*2*2);   // 64ch * NS * {sum,sum2} doubles
    (void)ws_size; (void)in_sizes; (void)n_in; (void)out_size;

    dim3 blk(256);
    dim3 gpix(HW/256, Bn);
    dim3 gtile(16,16,Bn);
    dim3 gapply16(HW/1024,16,Bn), gapply64(HW/1024,64,Bn);
    const long long bs16 = 16LL*HW, bs64 = 64LL*HW;

    auto bn_stats = [&](const float* x, int C){
        bn_stats_part<<<dim3(C,NS),blk,0,stream>>>(x, C, part);
        bn_finalize<<<1,64,0,stream>>>(part, C, mr);
    };

    // Stage A: hf_p = relu(bn(conv1x1(hf)))
    conv1x1_k<64,16><<<gpix,blk,0,stream>>>(hf, w_conv1_1, b_conv1_1, hf_p);
    bn_stats(hf_p, 16);
    bn_apply_k<<<gapply16,blk,0,stream>>>(hf_p, mr, 16, nullptr,0, nullptr,0, hf_p, 1);

    for(int k=0;k<4;k++){
        const float* prev; long long prev_bs;
        if (k==0){ prev = lf;      prev_bs = bs64; }
        else     { prev = xk[k-1]; prev_bs = bs16; }
        // xb = conv3x3(cat(prev, hf_p))  [cat fused via dual-input conv]
        conv3_k<16,16,16,16,1><<<dim3(4,16,Bn),blk,0,stream>>>(
            prev, prev_bs, hf_p, nullptr, w_conv, nullptr, nullptr, nullptr, B16_0);
        bn_stats(B16_0, 16);
        const float* e1; long long e1bs; const float* e2 = nullptr; long long e2bs = 0;
        if (k==0){ e1 = lf + 16*HW; e1bs = bs64; }
        else if (k==3){ e1 = xk[2]; e1bs = bs16; }
        else { e1 = xk[k-1]; e1bs = bs16; e2 = lf + (size_t)(k+1)*16*HW; e2bs = bs64; }
        bn_apply_k<<<gapply16,blk,0,stream>>>(B16_0, mr, 16, e1,e1bs, e2,e2bs, B16_0, 0); // t
        // offset conv (has bias, no bn)
        conv3_k<16,0,18,18,1><<<dim3(4,16,Bn),blk,0,stream>>>(
            B16_0, bs16, nullptr, nullptr, w_offset, b_offset, nullptr, nullptr, Boff);
        deform_k<<<gtile,blk,0,stream>>>(B16_0, Boff, w_deform, B16_1);
        // dilated conv
        switch(k){
        case 0: conv3_k<16,0,16,16,1><<<dim3(4,16,Bn),blk,0,stream>>>(B16_1, bs16, nullptr, nullptr, w_dil[0], nullptr, nullptr, nullptr, B16_2); break;
        case 1: conv3_k<16,0,16,16,2><<<dim3(4,16,Bn),blk,0,stream>>>(B16_1, bs16, nullptr, nullptr, w_dil[1], nullptr, nullptr, nullptr, B16_2); break;
        case 2: conv3_k<16,0,16,16,3><<<dim3(4,16,Bn),blk,0,stream>>>(B16_1, bs16, nullptr, nullptr, w_dil[2], nullptr, nullptr, nullptr, B16_2); break;
        case 3: conv3_k<16,0,16,16,4><<<dim3(4,16,Bn),blk,0,stream>>>(B16_1, bs16, nullptr, nullptr, w_dil[3], nullptr, nullptr, nullptr, B16_2); break;
        }
        bn_stats(B16_2, 16);
        bn_apply_k<<<gapply16,blk,0,stream>>>(B16_2, mr, 16, nullptr,0, nullptr,0, B16_2, 0);
        // conv1: 16 -> 64 (4 out-chunks)
        conv3_k<16,0,64,16,1><<<dim3(4,64,Bn),blk,0,stream>>>(
            B16_2, bs16, nullptr, nullptr, w_conv1, nullptr, nullptr, nullptr, B64_0);
        bn_stats(B64_0, 64);
        bn_apply_k<<<gapply64,blk,0,stream>>>(B64_0, mr, 64, nullptr,0, nullptr,0, B64_0, 0);
        // CBAM
        pool_k<<<Bn*64,blk,0,stream>>>(B64_0, pavg, pmax);
        ca_k<<<Bn,dim3(64),0,stream>>>(pavg, pmax, w_fc1, w_fc2, ca);
        spstats_k<<<dim3(256,Bn),blk,0,stream>>>(B64_0, ca, spm, spx);
        spconv_k<<<gtile,blk,0,stream>>>(spm, spx, w_sp, sa);
        // conv2 with fused ca (per-channel) and sa (per-pixel) input scaling
        conv3_k<64,0,16,16,1><<<dim3(4,16,Bn),blk,0,stream>>>(
            B64_0, bs64, nullptr, nullptr, w_conv2, nullptr, ca, sa, B16_1);
        bn_stats(B16_1, 16);
        bn_apply_k<<<gapply16,blk,0,stream>>>(B16_1, mr, 16, nullptr,0, nullptr,0, xk[k], 0);
    }

    // Final: xx = relu(bn(conv1x1(cat4))), out = bn(conv3x3(lf + xx))
    cat4_k<<<dim3(HW/1024,64,Bn),blk,0,stream>>>(xk[0], xk[1], xk[2], xk[3], B64F);
    conv1x1_k<64,64><<<gpix,blk,0,stream>>>(B64F, w_conv1_2, b_conv1_2, B64_0);
    bn_stats(B64_0, 64);
    bn_apply_k<<<gapply64,blk,0,stream>>>(B64_0, mr, 64, nullptr,0, nullptr,0, B64_0, 1); // xx
    conv3_k<64,0,64,16,1><<<dim3(4,64,Bn),blk,0,stream>>>(
        lf, bs64, nullptr, B64_0, w_conv3_3, nullptr, nullptr, nullptr, B64F);
    bn_stats(B64F, 64);
    bn_apply_k<<<gapply64,blk,0,stream>>>(B64F, mr, 64, nullptr,0, nullptr,0, out, 0);
}